// Round 1
// baseline (706.745 us; speedup 1.0000x reference)
//
#include <hip/hip_runtime.h>
#include <math.h>

// ---------------- workspace layout (in 4-byte units) ----------------
// CG dense: 729 floats at [0]
// TMP entries: 54 slots x 40 int2 at int offset 1024  (ends 1024+4320=5344)
// HDR ints at 5376: [0..5]=npairs[6], [6..59]=koff[54], [60..113]=poff[54],
//                   [114..383]=pcnt5[54*5], [384]=total
// ENT compact: 512 int2 at int offset 6144 (byte 24576, 8-aligned)
#define CG_OFF  0
#define TMP_OFF 1024
#define TMP_CAP 40
#define HDR_OFF 5376
#define ENT_OFF 6144

__device__ inline int deg_of(int A){ return (A==0) ? 0 : (A<4 ? 1 : 2); }

__device__ inline double factd(int n){
  double r = 1.0;
  for (int i = 2; i <= n; ++i) r *= (double)i;
  return r;
}

__device__ double cg_cplx(int l1,int m1,int l2,int m2,int l3,int m3){
  if (m1 + m2 != m3) return 0.0;
  if (l3 < abs(l1-l2) || l3 > l1+l2) return 0.0;
  double pref = (double)(2*l3+1) * factd(l1+l2-l3)*factd(l1-l2+l3)*factd(-l1+l2+l3)
                / factd(l1+l2+l3+1);
  pref *= factd(l3+m3)*factd(l3-m3)*factd(l1-m1)*factd(l1+m1)*factd(l2-m2)*factd(l2+m2);
  double s = 0.0;
  int k0 = max(0, max(l2-l3-m1, l1-l3+m2));
  int k1 = min(l1+l2-l3, min(l1-m1, l2+m2));
  for (int k = k0; k <= k1; ++k){
    double d = factd(k)*factd(l1+l2-l3-k)*factd(l1-m1-k)*factd(l2+m2-k)
               *factd(l3-l2+m1+k)*factd(l3-l1-m2+k);
    s += ((k & 1) ? -1.0 : 1.0) / d;
  }
  return sqrt(pref) * s;
}

// real<-complex change-of-basis entry U[l](row i, col m). Purely real or imag.
__device__ inline void u_ent(int l, int i, int m, double* re, double* im){
  *re = 0.0; *im = 0.0;
  const double s = 0.70710678118654752440;
  int mi = i - l;
  if (mi == 0){ if (m == 0) *re = 1.0; return; }
  if (mi > 0){
    if (m == mi)       *re = ((mi & 1) ? -1.0 : 1.0) * s;
    else if (m == -mi) *re = s;
    return;
  }
  int mp = -mi;
  if (m == mi)      *im = s;                           // column -mp
  else if (m == mp) *im = -((mp & 1) ? -1.0 : 1.0) * s; // column +mp
}

// one thread per (A,B,C) element of the 9x9x9 real CG tensor
__global__ void cg_kernel(float* __restrict__ ws_f){
  int tid = blockIdx.x * blockDim.x + threadIdx.x;
  if (tid >= 729) return;
  int A = tid / 81, B = (tid / 9) % 9, C = tid % 9;
  int l1 = deg_of(A), i = A - l1*l1;
  int l2 = deg_of(B), j = B - l2*l2;
  int l3 = deg_of(C), k = C - l3*l3;
  double out = 0.0;
  if (l3 >= abs(l1-l2) && l3 <= l1+l2){
    int mi = i - l1, mj = j - l2;
    int alist[2]; int na = (mi == 0) ? 1 : 2; alist[0] = mi; alist[1] = -mi;
    int blist[2]; int nb = (mj == 0) ? 1 : 2; blist[0] = mj; blist[1] = -mj;
    double tr = 0.0, ti = 0.0;
    for (int ai = 0; ai < na; ++ai){
      for (int bi = 0; bi < nb; ++bi){
        int a = alist[ai], b = blist[bi];
        int c = a + b;
        if (abs(c) > l3) continue;
        double u3r, u3i; u_ent(l3, k, c, &u3r, &u3i);
        if (u3r == 0.0 && u3i == 0.0) continue;
        double cgv = cg_cplx(l1, a, l2, b, l3, c);
        if (cgv == 0.0) continue;
        double u1r, u1i; u_ent(l1, i, a, &u1r, &u1i);
        double u2r, u2i; u_ent(l2, j, b, &u2r, &u2i);
        double pr = u1r*u2r - u1i*u2i;
        double pi = u1r*u2i + u1i*u2r;
        // multiply by conj(u3)
        double qr = pr*u3r + pi*u3i;
        double qi = pi*u3r - pr*u3i;
        tr += qr * cgv; ti += qi * cgv;
      }
    }
    out = (((l1+l2+l3) & 1) == 0) ? tr : ti;
  }
  ws_f[CG_OFF + A*81 + B*9 + C] = (float)out;
}

// build compact sparse lists grouped by output group g=(r*3+l3), then (l1,l2), then c
__global__ void build_lists(float* __restrict__ ws_f, int* __restrict__ ws_i){
  int tid = threadIdx.x;
  const float* cg = ws_f + CG_OFF;
  int2* tmp = (int2*)(ws_i + TMP_OFF);
  int* hdr = ws_i + HDR_OFF;
  __shared__ int cnts[54][5];
  if (tid < 54){
    int g = tid / 9, p = tid % 9;
    int r = g / 3, l3 = g % 3;
    int l1 = p / 3, l2 = p % 3;
    int cnt5[5] = {0,0,0,0,0};
    bool ok = (((l1 + l2) & 1) == r) && (l3 >= abs(l1-l2)) && (l3 <= l1+l2);
    int total = 0;
    if (ok){
      for (int k = 0; k < 2*l3+1; ++k){
        for (int i = 0; i < 2*l1+1; ++i){
          for (int j = 0; j < 2*l2+1; ++j){
            int A = l1*l1 + i, B = l2*l2 + j, Cc = l3*l3 + k;
            float v = cg[A*81 + B*9 + Cc];
            if (fabsf(v) > 1e-8f && total < TMP_CAP){
              tmp[tid*TMP_CAP + total] = make_int2(A | (B << 4), __float_as_int(v));
              ++total; ++cnt5[k];
            }
          }
        }
      }
    }
    for (int k = 0; k < 5; ++k) cnts[tid][k] = cnt5[k];
  }
  __syncthreads();
  if (tid == 0){
    int2* ent = (int2*)(ws_i + ENT_OFF);
    int off = 0;
    for (int g = 0; g < 6; ++g){
      int np = 0;
      for (int p = 0; p < 9; ++p){
        int s = g*9 + p;
        int tot = cnts[s][0]+cnts[s][1]+cnts[s][2]+cnts[s][3]+cnts[s][4];
        if (tot > 0){
          int l1 = p/3, l2 = p%3, l3 = g%3, r = g/3;
          int idx = g*9 + np;
          hdr[6 + idx]  = ((l1*3 + l2)*2 + r)*3 + l3;  // koff into kernel tensor
          hdr[60 + idx] = off;                          // entry start
          for (int k = 0; k < 5; ++k) hdr[114 + idx*5 + k] = cnts[s][k];
          for (int e = 0; e < tot; ++e) ent[off + e] = tmp[s*TMP_CAP + e];
          off += tot;
          ++np;
        }
      }
      hdr[g] = np;
    }
    hdr[384] = off;
  }
}

#define NF2 64   // 128 floats = 64 float2 per (n, channel)

__global__ __launch_bounds__(256) void tp_main(
    const float* __restrict__ xg, const float* __restrict__ yg,
    const float* __restrict__ Kg, float* __restrict__ outg,
    const int* __restrict__ ws_i){
  __shared__ int s_np[6];
  __shared__ int s_koff[54], s_poff[54];
  __shared__ int s_pc5[270];
  __shared__ int2 s_ent[512];

  const int* hdr = ws_i + HDR_OFF;
  const int2* ent_g = (const int2*)(ws_i + ENT_OFF);
  int tid = threadIdx.x;
  for (int t = tid; t < 6;   t += 256) s_np[t] = hdr[t];
  for (int t = tid; t < 54;  t += 256){ s_koff[t] = hdr[6+t]; s_poff[t] = hdr[60+t]; }
  for (int t = tid; t < 270; t += 256) s_pc5[t] = hdr[114+t];
  for (int t = tid; t < 512; t += 256) s_ent[t] = ent_g[t];
  __syncthreads();

  int fi = tid & 63;          // float2 lane within feature dim
  int n  = blockIdx.x * 4 + (tid >> 6);

  const float2* x2 = (const float2*)xg + (size_t)n * 9 * NF2 + fi;
  const float2* y2 = (const float2*)yg + (size_t)n * 9 * NF2 + fi;
  const float2* K2 = (const float2*)Kg;
  float2* out2 = (float2*)outg + (size_t)n * 18 * NF2 + fi;

  float2 xv[9], yv[9];
  #pragma unroll
  for (int a = 0; a < 9; ++a){ xv[a] = x2[a*NF2]; yv[a] = y2[a*NF2]; }

  #pragma unroll
  for (int g = 0; g < 6; ++g){
    const int r = g / 3, l3 = g % 3, nm = 2*l3 + 1;
    float2 acc[5];
    #pragma unroll
    for (int c = 0; c < nm; ++c){ acc[c].x = 0.f; acc[c].y = 0.f; }
    int np = s_np[g];
    for (int p = 0; p < np; ++p){
      int idx = g*9 + p;
      int off = s_poff[idx];
      float2 kv = K2[s_koff[idx]*NF2 + fi];
      #pragma unroll
      for (int c = 0; c < nm; ++c){
        int cnt = s_pc5[idx*5 + c];
        float Sx = 0.f, Sy = 0.f;
        for (int e = 0; e < cnt; ++e){
          int2 E = s_ent[off + e];
          int A = E.x & 15, B = (E.x >> 4) & 15;
          float v = __int_as_float(E.y);
          Sx += v * xv[A].x * yv[B].x;
          Sy += v * xv[A].y * yv[B].y;
        }
        off += cnt;
        acc[c].x += kv.x * Sx;
        acc[c].y += kv.y * Sy;
      }
    }
    int obase = (r*9 + l3*l3) * NF2;
    #pragma unroll
    for (int c = 0; c < nm; ++c) out2[obase + c*NF2] = acc[c];
  }
}

extern "C" void kernel_launch(void* const* d_in, const int* in_sizes, int n_in,
                              void* d_out, int out_size, void* d_ws, size_t ws_size,
                              hipStream_t stream){
  const float* x = (const float*)d_in[0];   // (32768, 1, 9, 128)
  const float* y = (const float*)d_in[1];   // (32768, 1, 9, 128)
  const float* K = (const float*)d_in[2];   // (1,3,1,3,2,3,128)
  float* out = (float*)d_out;               // (32768, 2, 9, 128)
  float* ws_f = (float*)d_ws;
  int*   ws_i = (int*)d_ws;

  hipLaunchKernelGGL(cg_kernel,   dim3(1), dim3(768), 0, stream, ws_f);
  hipLaunchKernelGGL(build_lists, dim3(1), dim3(64),  0, stream, ws_f, ws_i);
  hipLaunchKernelGGL(tp_main, dim3(32768/4), dim3(256), 0, stream, x, y, K, out, ws_i);
}

// Round 2
// 130.802 us; speedup vs baseline: 5.4031x; 5.4031x over previous
//
#include <hip/hip_runtime.h>
#include <math.h>

// ---------------- workspace layout ----------------
// CG dense: 729 floats at ws_f[0..728]
#define NF2 64   // 128 floats = 64 float2 per (n, channel)

__device__ inline int deg_of(int A){ return (A==0) ? 0 : (A<4 ? 1 : 2); }

__device__ inline double factd(int n){
  double r = 1.0;
  for (int i = 2; i <= n; ++i) r *= (double)i;
  return r;
}

__device__ double cg_cplx(int l1,int m1,int l2,int m2,int l3,int m3){
  if (m1 + m2 != m3) return 0.0;
  if (l3 < abs(l1-l2) || l3 > l1+l2) return 0.0;
  double pref = (double)(2*l3+1) * factd(l1+l2-l3)*factd(l1-l2+l3)*factd(-l1+l2+l3)
                / factd(l1+l2+l3+1);
  pref *= factd(l3+m3)*factd(l3-m3)*factd(l1-m1)*factd(l1+m1)*factd(l2-m2)*factd(l2+m2);
  double s = 0.0;
  int k0 = max(0, max(l2-l3-m1, l1-l3+m2));
  int k1 = min(l1+l2-l3, min(l1-m1, l2+m2));
  for (int k = k0; k <= k1; ++k){
    double d = factd(k)*factd(l1+l2-l3-k)*factd(l1-m1-k)*factd(l2+m2-k)
               *factd(l3-l2+m1+k)*factd(l3-l1-m2+k);
    s += ((k & 1) ? -1.0 : 1.0) / d;
  }
  return sqrt(pref) * s;
}

// real<-complex change-of-basis entry U[l](row i, col m). Purely real or imag.
__device__ inline void u_ent(int l, int i, int m, double* re, double* im){
  *re = 0.0; *im = 0.0;
  const double s = 0.70710678118654752440;
  int mi = i - l;
  if (mi == 0){ if (m == 0) *re = 1.0; return; }
  if (mi > 0){
    if (m == mi)       *re = ((mi & 1) ? -1.0 : 1.0) * s;
    else if (m == -mi) *re = s;
    return;
  }
  int mp = -mi;
  if (m == mi)      *im = s;                            // column -mp
  else if (m == mp) *im = -((mp & 1) ? -1.0 : 1.0) * s; // column +mp
}

// one thread per (A,B,C) element of the 9x9x9 real CG tensor
__global__ void cg_kernel(float* __restrict__ ws_f){
  int tid = blockIdx.x * blockDim.x + threadIdx.x;
  if (tid >= 729) return;
  int A = tid / 81, B = (tid / 9) % 9, C = tid % 9;
  int l1 = deg_of(A), i = A - l1*l1;
  int l2 = deg_of(B), j = B - l2*l2;
  int l3 = deg_of(C), k = C - l3*l3;
  double out = 0.0;
  if (l3 >= abs(l1-l2) && l3 <= l1+l2){
    int mi = i - l1, mj = j - l2;
    int alist[2]; int na = (mi == 0) ? 1 : 2; alist[0] = mi; alist[1] = -mi;
    int blist[2]; int nb = (mj == 0) ? 1 : 2; blist[0] = mj; blist[1] = -mj;
    double tr = 0.0, ti = 0.0;
    for (int ai = 0; ai < na; ++ai){
      for (int bi = 0; bi < nb; ++bi){
        int a = alist[ai], b = blist[bi];
        int c = a + b;
        if (abs(c) > l3) continue;
        double u3r, u3i; u_ent(l3, k, c, &u3r, &u3i);
        if (u3r == 0.0 && u3i == 0.0) continue;
        double cgv = cg_cplx(l1, a, l2, b, l3, c);
        if (cgv == 0.0) continue;
        double u1r, u1i; u_ent(l1, i, a, &u1r, &u1i);
        double u2r, u2i; u_ent(l2, j, b, &u2r, &u2i);
        double pr = u1r*u2r - u1i*u2i;
        double pi = u1r*u2i + u1i*u2r;
        // multiply by conj(u3)
        double qr = pr*u3r + pi*u3i;
        double qi = pi*u3r - pr*u3i;
        tr += qr * cgv; ti += qi * cgv;
      }
    }
    out = (((l1+l2+l3) & 1) == 0) ? tr : ti;
  }
  ws_f[A*81 + B*9 + C] = (float)out;
}

// ---------------- main tensor-product kernel ----------------
// Fully compile-time-unrolled sparse coupling. The nonzero SUPPORT of the
// real CG tensor obeys exact selection rules:
//   |m3| in { mu1+mu2, |mu1-mu2| }  (from complex support {+-m1} x {+-m2})
//   sin/cos type: s3 = ((l1+l2+l3)&1) ^ s1 ^ s2  (phase i^(s1+s2+s3) must
//   match the real/imag part taken), with the m3=0 sin row nonexistent.
// We unroll a (safe) superset of this support; values come from the
// device-computed cg table at compile-time-constant offsets (uniform ->
// scalar loads). All x/y/acc indices are compile-time -> pure registers.

template<int l1,int l2,int l3,int r>
__device__ __forceinline__ void do_path(const float* __restrict__ cg,
    const float2* __restrict__ K2, int fi,
    const float2* xv, const float2* yv, float2* acc){
  float2 S[2*l3+1];
  #pragma unroll
  for (int k = 0; k < 2*l3+1; ++k){ S[k].x = 0.f; S[k].y = 0.f; }
  #pragma unroll
  for (int i = 0; i < 2*l1+1; ++i){
    #pragma unroll
    for (int j = 0; j < 2*l2+1; ++j){
      const int m1 = i - l1, m2 = j - l2;
      const int mu1 = m1 < 0 ? -m1 : m1;
      const int mu2 = m2 < 0 ? -m2 : m2;
      const int s1 = (m1 < 0) ? 1 : 0, s2 = (m2 < 0) ? 1 : 0;
      const int s3 = (((l1+l2+l3) & 1) ? 1 : 0) ^ s1 ^ s2;
      #pragma unroll
      for (int t = 0; t < 2; ++t){
        const int lo  = (mu1 > mu2) ? (mu1 - mu2) : (mu2 - mu1);
        const int mu3 = t ? lo : (mu1 + mu2);
        if (t && lo == mu1 + mu2) continue;   // dedupe when a mu is 0
        if (mu3 > l3) continue;
        if (s3 && mu3 == 0) continue;         // no sin-type m3=0 row
        const int k = (s3 ? -mu3 : mu3) + l3;
        const int A = l1*l1 + i, B = l2*l2 + j, C = l3*l3 + k;
        const float v = cg[A*81 + B*9 + C];
        S[k].x += v * xv[A].x * yv[B].x;
        S[k].y += v * xv[A].y * yv[B].y;
      }
    }
  }
  const int koff = ((l1*3 + l2)*2 + r)*3 + l3;
  const float2 kv = K2[koff*NF2 + fi];
  #pragma unroll
  for (int k = 0; k < 2*l3+1; ++k){
    acc[k].x += kv.x * S[k].x;
    acc[k].y += kv.y * S[k].y;
  }
}

__global__ __launch_bounds__(256) void tp_main(
    const float* __restrict__ xg, const float* __restrict__ yg,
    const float* __restrict__ Kg, float* __restrict__ outg,
    const float* __restrict__ cg){
  const int tid = threadIdx.x;
  const int fi  = tid & 63;            // float2 lane within feature dim
  const int n   = blockIdx.x * 4 + (tid >> 6);

  const float2* x2 = (const float2*)xg + (size_t)n * 9 * NF2 + fi;
  const float2* y2 = (const float2*)yg + (size_t)n * 9 * NF2 + fi;
  const float2* K2 = (const float2*)Kg;
  float2* out2 = (float2*)outg + (size_t)n * 18 * NF2 + fi;

  float2 xv[9], yv[9];
  #pragma unroll
  for (int a = 0; a < 9; ++a){ xv[a] = x2[a*NF2]; yv[a] = y2[a*NF2]; }

  float2 acc[5];
  const float2 z2 = make_float2(0.f, 0.f);

  // ---- group (r=0, l3=0): paths (0,0),(1,1),(2,2) -> channel 0
  acc[0] = z2;
  do_path<0,0,0,0>(cg, K2, fi, xv, yv, acc);
  do_path<1,1,0,0>(cg, K2, fi, xv, yv, acc);
  do_path<2,2,0,0>(cg, K2, fi, xv, yv, acc);
  out2[0*NF2] = acc[0];

  // ---- group (r=0, l3=1): paths (1,1),(2,2) -> channels 1..3
  #pragma unroll
  for (int k = 0; k < 3; ++k) acc[k] = z2;
  do_path<1,1,1,0>(cg, K2, fi, xv, yv, acc);
  do_path<2,2,1,0>(cg, K2, fi, xv, yv, acc);
  #pragma unroll
  for (int k = 0; k < 3; ++k) out2[(1+k)*NF2] = acc[k];

  // ---- group (r=0, l3=2): paths (1,1),(2,2),(0,2),(2,0) -> channels 4..8
  #pragma unroll
  for (int k = 0; k < 5; ++k) acc[k] = z2;
  do_path<1,1,2,0>(cg, K2, fi, xv, yv, acc);
  do_path<2,2,2,0>(cg, K2, fi, xv, yv, acc);
  do_path<0,2,2,0>(cg, K2, fi, xv, yv, acc);
  do_path<2,0,2,0>(cg, K2, fi, xv, yv, acc);
  #pragma unroll
  for (int k = 0; k < 5; ++k) out2[(4+k)*NF2] = acc[k];

  // ---- group (r=1, l3=0): no parity-allowed paths -> channel 9 is zero
  out2[9*NF2] = z2;

  // ---- group (r=1, l3=1): paths (0,1),(1,0),(1,2),(2,1) -> channels 10..12
  #pragma unroll
  for (int k = 0; k < 3; ++k) acc[k] = z2;
  do_path<0,1,1,1>(cg, K2, fi, xv, yv, acc);
  do_path<1,0,1,1>(cg, K2, fi, xv, yv, acc);
  do_path<1,2,1,1>(cg, K2, fi, xv, yv, acc);
  do_path<2,1,1,1>(cg, K2, fi, xv, yv, acc);
  #pragma unroll
  for (int k = 0; k < 3; ++k) out2[(10+k)*NF2] = acc[k];

  // ---- group (r=1, l3=2): paths (1,2),(2,1) -> channels 13..17
  #pragma unroll
  for (int k = 0; k < 5; ++k) acc[k] = z2;
  do_path<1,2,2,1>(cg, K2, fi, xv, yv, acc);
  do_path<2,1,2,1>(cg, K2, fi, xv, yv, acc);
  #pragma unroll
  for (int k = 0; k < 5; ++k) out2[(13+k)*NF2] = acc[k];
}

extern "C" void kernel_launch(void* const* d_in, const int* in_sizes, int n_in,
                              void* d_out, int out_size, void* d_ws, size_t ws_size,
                              hipStream_t stream){
  const float* x = (const float*)d_in[0];   // (32768, 1, 9, 128)
  const float* y = (const float*)d_in[1];   // (32768, 1, 9, 128)
  const float* K = (const float*)d_in[2];   // (1,3,1,3,2,3,128)
  float* out = (float*)d_out;               // (32768, 2, 9, 128)
  float* ws_f = (float*)d_ws;

  hipLaunchKernelGGL(cg_kernel, dim3(1), dim3(768), 0, stream, ws_f);
  hipLaunchKernelGGL(tp_main, dim3(32768/4), dim3(256), 0, stream,
                     x, y, K, out, ws_f);
}

// Round 4
// 125.470 us; speedup vs baseline: 5.6328x; 1.0425x over previous
//
#include <hip/hip_runtime.h>
#include <math.h>

// ---------------- workspace layout ----------------
// CG dense: 729 floats at ws_f[0..728]
#define NF4 32   // 128 floats = 32 float4 per (n, channel)

typedef float f4 __attribute__((ext_vector_type(4)));  // clang vector: nontemporal-builtin OK

__device__ inline int deg_of(int A){ return (A==0) ? 0 : (A<4 ? 1 : 2); }

__device__ inline double factd(int n){
  double r = 1.0;
  for (int i = 2; i <= n; ++i) r *= (double)i;
  return r;
}

__device__ double cg_cplx(int l1,int m1,int l2,int m2,int l3,int m3){
  if (m1 + m2 != m3) return 0.0;
  if (l3 < abs(l1-l2) || l3 > l1+l2) return 0.0;
  double pref = (double)(2*l3+1) * factd(l1+l2-l3)*factd(l1-l2+l3)*factd(-l1+l2+l3)
                / factd(l1+l2+l3+1);
  pref *= factd(l3+m3)*factd(l3-m3)*factd(l1-m1)*factd(l1+m1)*factd(l2-m2)*factd(l2+m2);
  double s = 0.0;
  int k0 = max(0, max(l2-l3-m1, l1-l3+m2));
  int k1 = min(l1+l2-l3, min(l1-m1, l2+m2));
  for (int k = k0; k <= k1; ++k){
    double d = factd(k)*factd(l1+l2-l3-k)*factd(l1-m1-k)*factd(l2+m2-k)
               *factd(l3-l2+m1+k)*factd(l3-l1-m2+k);
    s += ((k & 1) ? -1.0 : 1.0) / d;
  }
  return sqrt(pref) * s;
}

// real<-complex change-of-basis entry U[l](row i, col m). Purely real or imag.
__device__ inline void u_ent(int l, int i, int m, double* re, double* im){
  *re = 0.0; *im = 0.0;
  const double s = 0.70710678118654752440;
  int mi = i - l;
  if (mi == 0){ if (m == 0) *re = 1.0; return; }
  if (mi > 0){
    if (m == mi)       *re = ((mi & 1) ? -1.0 : 1.0) * s;
    else if (m == -mi) *re = s;
    return;
  }
  int mp = -mi;
  if (m == mi)      *im = s;                            // column -mp
  else if (m == mp) *im = -((mp & 1) ? -1.0 : 1.0) * s; // column +mp
}

// one thread per (A,B,C) element of the 9x9x9 real CG tensor
__global__ void cg_kernel(float* __restrict__ ws_f){
  int tid = blockIdx.x * blockDim.x + threadIdx.x;
  if (tid >= 729) return;
  int A = tid / 81, B = (tid / 9) % 9, C = tid % 9;
  int l1 = deg_of(A), i = A - l1*l1;
  int l2 = deg_of(B), j = B - l2*l2;
  int l3 = deg_of(C), k = C - l3*l3;
  double out = 0.0;
  if (l3 >= abs(l1-l2) && l3 <= l1+l2){
    int mi = i - l1, mj = j - l2;
    int alist[2]; int na = (mi == 0) ? 1 : 2; alist[0] = mi; alist[1] = -mi;
    int blist[2]; int nb = (mj == 0) ? 1 : 2; blist[0] = mj; blist[1] = -mj;
    double tr = 0.0, ti = 0.0;
    for (int ai = 0; ai < na; ++ai){
      for (int bi = 0; bi < nb; ++bi){
        int a = alist[ai], b = blist[bi];
        int c = a + b;
        if (abs(c) > l3) continue;
        double u3r, u3i; u_ent(l3, k, c, &u3r, &u3i);
        if (u3r == 0.0 && u3i == 0.0) continue;
        double cgv = cg_cplx(l1, a, l2, b, l3, c);
        if (cgv == 0.0) continue;
        double u1r, u1i; u_ent(l1, i, a, &u1r, &u1i);
        double u2r, u2i; u_ent(l2, j, b, &u2r, &u2i);
        double pr = u1r*u2r - u1i*u2i;
        double pi = u1r*u2i + u1i*u2r;
        // multiply by conj(u3)
        double qr = pr*u3r + pi*u3i;
        double qi = pi*u3r - pr*u3i;
        tr += qr * cgv; ti += qi * cgv;
      }
    }
    out = (((l1+l2+l3) & 1) == 0) ? tr : ti;
  }
  ws_f[A*81 + B*9 + C] = (float)out;
}

// ---------------- main tensor-product kernel ----------------
// Fully compile-time-unrolled sparse coupling (selection rules give the exact
// support; values come from the device-computed cg table at compile-time-
// constant offsets -> scalar loads). All x/y/acc indices compile-time ->
// pure registers. float4 (16B/lane) nontemporal streams for x, y, out.

__device__ __forceinline__ void fma4s(f4& s, float v, const f4& a, const f4& b){
  s += v * a * b;
}

template<int l1,int l2,int l3,int r>
__device__ __forceinline__ void do_path(const float* __restrict__ cg,
    const f4* __restrict__ K4, int fi,
    const f4* xv, const f4* yv, f4* acc){
  f4 S[2*l3+1];
  #pragma unroll
  for (int k = 0; k < 2*l3+1; ++k) S[k] = (f4)0.f;
  #pragma unroll
  for (int i = 0; i < 2*l1+1; ++i){
    #pragma unroll
    for (int j = 0; j < 2*l2+1; ++j){
      const int m1 = i - l1, m2 = j - l2;
      const int mu1 = m1 < 0 ? -m1 : m1;
      const int mu2 = m2 < 0 ? -m2 : m2;
      const int s1 = (m1 < 0) ? 1 : 0, s2 = (m2 < 0) ? 1 : 0;
      const int s3 = (((l1+l2+l3) & 1) ? 1 : 0) ^ s1 ^ s2;
      #pragma unroll
      for (int t = 0; t < 2; ++t){
        const int lo  = (mu1 > mu2) ? (mu1 - mu2) : (mu2 - mu1);
        const int mu3 = t ? lo : (mu1 + mu2);
        if (t && lo == mu1 + mu2) continue;   // dedupe when a mu is 0
        if (mu3 > l3) continue;
        if (s3 && mu3 == 0) continue;         // no sin-type m3=0 row
        const int k = (s3 ? -mu3 : mu3) + l3;
        const int A = l1*l1 + i, B = l2*l2 + j, C = l3*l3 + k;
        const float v = cg[A*81 + B*9 + C];
        fma4s(S[k], v, xv[A], yv[B]);
      }
    }
  }
  const int koff = ((l1*3 + l2)*2 + r)*3 + l3;
  const f4 kv = K4[koff*NF4 + fi];
  #pragma unroll
  for (int k = 0; k < 2*l3+1; ++k) acc[k] += kv * S[k];
}

__global__ __launch_bounds__(256) void tp_main(
    const float* __restrict__ xg, const float* __restrict__ yg,
    const float* __restrict__ Kg, float* __restrict__ outg,
    const float* __restrict__ cg){
  const int tid = threadIdx.x;
  const int fi  = tid & 31;            // float4 lane within feature dim
  const int n   = blockIdx.x * 8 + (tid >> 5);

  const f4* x4 = (const f4*)xg + (size_t)n * 9 * NF4 + fi;
  const f4* y4 = (const f4*)yg + (size_t)n * 9 * NF4 + fi;
  const f4* K4 = (const f4*)Kg;
  f4* out4 = (f4*)outg + (size_t)n * 18 * NF4 + fi;

  f4 xv[9], yv[9];
  #pragma unroll
  for (int a = 0; a < 9; ++a){
    xv[a] = __builtin_nontemporal_load(&x4[a*NF4]);
    yv[a] = __builtin_nontemporal_load(&y4[a*NF4]);
  }

  f4 acc[5];
  const f4 z4 = (f4)0.f;

  // ---- group (r=0, l3=0): paths (0,0),(1,1),(2,2) -> channel 0
  acc[0] = z4;
  do_path<0,0,0,0>(cg, K4, fi, xv, yv, acc);
  do_path<1,1,0,0>(cg, K4, fi, xv, yv, acc);
  do_path<2,2,0,0>(cg, K4, fi, xv, yv, acc);
  __builtin_nontemporal_store(acc[0], &out4[0*NF4]);

  // ---- group (r=0, l3=1): paths (1,1),(2,2) -> channels 1..3
  #pragma unroll
  for (int k = 0; k < 3; ++k) acc[k] = z4;
  do_path<1,1,1,0>(cg, K4, fi, xv, yv, acc);
  do_path<2,2,1,0>(cg, K4, fi, xv, yv, acc);
  #pragma unroll
  for (int k = 0; k < 3; ++k) __builtin_nontemporal_store(acc[k], &out4[(1+k)*NF4]);

  // ---- group (r=0, l3=2): paths (1,1),(2,2),(0,2),(2,0) -> channels 4..8
  #pragma unroll
  for (int k = 0; k < 5; ++k) acc[k] = z4;
  do_path<1,1,2,0>(cg, K4, fi, xv, yv, acc);
  do_path<2,2,2,0>(cg, K4, fi, xv, yv, acc);
  do_path<0,2,2,0>(cg, K4, fi, xv, yv, acc);
  do_path<2,0,2,0>(cg, K4, fi, xv, yv, acc);
  #pragma unroll
  for (int k = 0; k < 5; ++k) __builtin_nontemporal_store(acc[k], &out4[(4+k)*NF4]);

  // ---- group (r=1, l3=0): no parity-allowed paths -> channel 9 is zero
  __builtin_nontemporal_store(z4, &out4[9*NF4]);

  // ---- group (r=1, l3=1): paths (0,1),(1,0),(1,2),(2,1) -> channels 10..12
  #pragma unroll
  for (int k = 0; k < 3; ++k) acc[k] = z4;
  do_path<0,1,1,1>(cg, K4, fi, xv, yv, acc);
  do_path<1,0,1,1>(cg, K4, fi, xv, yv, acc);
  do_path<1,2,1,1>(cg, K4, fi, xv, yv, acc);
  do_path<2,1,1,1>(cg, K4, fi, xv, yv, acc);
  #pragma unroll
  for (int k = 0; k < 3; ++k) __builtin_nontemporal_store(acc[k], &out4[(10+k)*NF4]);

  // ---- group (r=1, l3=2): paths (1,2),(2,1) -> channels 13..17
  #pragma unroll
  for (int k = 0; k < 5; ++k) acc[k] = z4;
  do_path<1,2,2,1>(cg, K4, fi, xv, yv, acc);
  do_path<2,1,2,1>(cg, K4, fi, xv, yv, acc);
  #pragma unroll
  for (int k = 0; k < 5; ++k) __builtin_nontemporal_store(acc[k], &out4[(13+k)*NF4]);
}

extern "C" void kernel_launch(void* const* d_in, const int* in_sizes, int n_in,
                              void* d_out, int out_size, void* d_ws, size_t ws_size,
                              hipStream_t stream){
  const float* x = (const float*)d_in[0];   // (32768, 1, 9, 128)
  const float* y = (const float*)d_in[1];   // (32768, 1, 9, 128)
  const float* K = (const float*)d_in[2];   // (1,3,1,3,2,3,128)
  float* out = (float*)d_out;               // (32768, 2, 9, 128)
  float* ws_f = (float*)d_ws;

  hipLaunchKernelGGL(cg_kernel, dim3(1), dim3(768), 0, stream, ws_f);
  hipLaunchKernelGGL(tp_main, dim3(32768/8), dim3(256), 0, stream,
                     x, y, K, out, ws_f);
}